// Round 6
// baseline (472.413 us; speedup 1.0000x reference)
//
#include <hip/hip_runtime.h>
#include <hip/hip_bf16.h>

// ---------------------------------------------------------------------------
// AttnBlock: GroupNorm -> fused qkv 1x1conv -> softmax(QK^T*scale)@V -> proj+res
// B=4, HW=4096, C=512, G=32. bf16 MFMA, fp32 accum.
// Round 6: gemm geometry BM=256 x BN=128, 4 waves each owning a 128x64 output
// tile (2x MFMA work per LDS byte and per barrier vs 64x64). Pipeline: 3-buf,
// depth-2 prefetch, counted s_waitcnt vmcnt(6) + raw s_barrier per K-step.
// T2 LDS swizzle (source-side, involution g^=(row>>1)&3) and T1 XCD remap kept.
// ---------------------------------------------------------------------------

typedef __attribute__((ext_vector_type(8))) short s16x8;  // 8 bf16
typedef __attribute__((ext_vector_type(4))) float f32x4;  // MFMA accum

__device__ inline ushort f2bf(float f) {
    union { float f; unsigned u; } v; v.f = f;
    unsigned r = (v.u + 0x7FFFu + ((v.u >> 16) & 1u)) >> 16;
    return (ushort)r;
}
__device__ inline float bf2f(ushort u) {
    union { unsigned u; float f; } v; v.u = ((unsigned)u) << 16;
    return v.f;
}

__device__ inline void gll16(const void* g, void* l) {
    __builtin_amdgcn_global_load_lds(
        (const __attribute__((address_space(1))) void*)g,
        (__attribute__((address_space(3))) void*)l, 16, 0, 0);
}

// ---------------------------------------------------------------------------
// GroupNorm stage 1: contiguous partial sums.
// ---------------------------------------------------------------------------
__global__ __launch_bounds__(256) void gn_part(const float* __restrict__ x,
                                               float2* __restrict__ partial) {
    int blk = blockIdx.x;
    int b = blk >> 6, chunk = blk & 63;
    const float* base = x + ((size_t)b * 4096 + chunk * 64) * 512;
    int t = threadIdx.x;
    int q = t & 127, ph = t >> 7;
    float s = 0.f, ss = 0.f;
    for (int p = ph; p < 64; p += 2) {
        float4 v = *(const float4*)(base + (size_t)p * 512 + q * 4);
        s  += v.x + v.y + v.z + v.w;
        ss += v.x * v.x + v.y * v.y + v.z * v.z + v.w * v.w;
    }
    __shared__ float ls[256], lss[256];
    ls[t] = s; lss[t] = ss;
    __syncthreads();
    if (t < 32) {
        float S1 = 0.f, S2 = 0.f;
        #pragma unroll
        for (int j = 0; j < 4; j++) {
            int i = t * 4 + j;
            S1 += ls[i] + ls[i + 128];
            S2 += lss[i] + lss[i + 128];
        }
        partial[(size_t)blk * 32 + t] = make_float2(S1, S2);
    }
}

__global__ void gn_reduce(const float2* __restrict__ partial,
                          float2* __restrict__ stats) {
    int i = threadIdx.x;   // b*32+g
    if (i < 128) {
        int b = i >> 5, g = i & 31;
        float S1 = 0.f, S2 = 0.f;
        for (int c = 0; c < 64; c++) {
            float2 p = partial[((size_t)(b * 64 + c)) * 32 + g];
            S1 += p.x; S2 += p.y;
        }
        float mean = S1 * (1.f / 65536.f);
        float var  = S2 * (1.f / 65536.f) - mean * mean;
        stats[i] = make_float2(mean, rsqrtf(var + 1e-5f));
    }
}

// ---------------------------------------------------------------------------
// GroupNorm apply + cast to bf16 h_
// ---------------------------------------------------------------------------
__global__ __launch_bounds__(256) void gn_apply(const float* __restrict__ x,
                                                const float* __restrict__ gamma,
                                                const float* __restrict__ beta,
                                                const float2* __restrict__ stats,
                                                ushort* __restrict__ h) {
    const int total = 4 * 4096 * 512 / 4;
    for (int i = blockIdx.x * blockDim.x + threadIdx.x; i < total;
         i += gridDim.x * blockDim.x) {
        int e = i * 4;
        int c = e & 511;
        int b = e >> 21;
        int g = c >> 4;
        float2 st = stats[b * 32 + g];
        float4 v  = *(const float4*)(x + (size_t)e);
        float4 ga = *(const float4*)(gamma + c);
        float4 be = *(const float4*)(beta + c);
        ushort4 o;
        o.x = f2bf((v.x - st.x) * st.y * ga.x + be.x);
        o.y = f2bf((v.y - st.x) * st.y * ga.y + be.y);
        o.z = f2bf((v.z - st.x) * st.y * ga.z + be.z);
        o.w = f2bf((v.w - st.x) * st.y * ga.w + be.w);
        ((ushort4*)h)[i] = o;
    }
}

// ---------------------------------------------------------------------------
// Weight prep: fp32 (K,N) -> bf16 (N,K). z<3 -> wcat slab (q scaled), z=3 -> wtp
// ---------------------------------------------------------------------------
__global__ void prep_w(const float* __restrict__ wq, const float* __restrict__ wk,
                       const float* __restrict__ wv, const float* __restrict__ wp,
                       ushort* __restrict__ wcat, ushort* __restrict__ wtp,
                       float qscale) {
    const float* src; ushort* dst; float al = 1.f;
    switch (blockIdx.z) {
        case 0: src = wq; dst = wcat;               al = qscale; break;
        case 1: src = wk; dst = wcat + 512 * 512;   break;
        case 2: src = wv; dst = wcat + 1024 * 512;  break;
        default: src = wp; dst = wtp;               break;
    }
    __shared__ float tile[32][33];
    int k0 = blockIdx.y * 32, n0 = blockIdx.x * 32;
    int tx = threadIdx.x, ty = threadIdx.y;
    #pragma unroll
    for (int i = 0; i < 4; i++)
        tile[ty + i * 8][tx] = src[(size_t)(k0 + ty + i * 8) * 512 + n0 + tx];
    __syncthreads();
    #pragma unroll
    for (int i = 0; i < 4; i++)
        dst[(size_t)(n0 + ty + i * 8) * 512 + k0 + tx] =
            f2bf(tile[tx][ty + i * 8] * al);
}

__global__ void bias_cat(const float* __restrict__ bq, const float* __restrict__ bk,
                         const float* __restrict__ bv, float* __restrict__ bcat,
                         float qscale) {
    int t = threadIdx.x;
    bcat[t]        = bq[t] * qscale;
    bcat[512 + t]  = bk[t];
    bcat[1024 + t] = bv[t];
}

// ---------------------------------------------------------------------------
// V transpose per batch: (4096 x 512, row stride ist) -> (512 x 4096) bf16
// ---------------------------------------------------------------------------
__global__ __launch_bounds__(256) void transpose_v(const ushort* __restrict__ v,
                                                   int ist,
                                                   ushort* __restrict__ vt) {
    __shared__ ushort tile[64][72];
    int b = blockIdx.z;
    int kv0 = blockIdx.x * 64, c0 = blockIdx.y * 64;
    const ushort* in = v + (size_t)b * 4096 * ist;
    ushort* out = vt + (size_t)b * 512 * 4096;
    int t = threadIdx.x;
    int c4 = t & 15, r = t >> 4;
    #pragma unroll
    for (int i = 0; i < 4; i++) {
        int row = r + i * 16;
        *(ushort4*)&tile[row][c4 * 4] =
            *(const ushort4*)(in + (size_t)(kv0 + row) * ist + c0 + c4 * 4);
    }
    __syncthreads();
    int kv4 = t & 15, rc = t >> 4;
    #pragma unroll
    for (int i = 0; i < 4; i++) {
        int c = rc + i * 16;
        ushort4 o;
        o.x = tile[kv4 * 4 + 0][c];
        o.y = tile[kv4 * 4 + 1][c];
        o.z = tile[kv4 * 4 + 2][c];
        o.w = tile[kv4 * 4 + 3][c];
        *(ushort4*)(out + (size_t)(c0 + c) * 4096 + kv0 + kv4 * 4) = o;
    }
}

// ---------------------------------------------------------------------------
// v6-pipe GEMM: C[z][m,n] = (sum_k A[z][m,k]*Bt[z][n,k] + bias[n])*alpha (+res)
// BM=256 x BN=128 tile, BK=32, 256 thr = 4 waves (2x2), per-wave 128x64 output
// (8x4 fragment grid, acc = 128 VGPR; a-frags processed in two halves).
// Triple-buffered LDS (72 KB -> 2 blocks/CU), depth-2 prefetch, counted
// s_waitcnt vmcnt(6) + raw s_barrier per K-step (6 loads/thread/stage).
// T2: LDS k-quad swizzle g ^= (row>>1)&3 on staging SOURCE addr + ds_read.
// T1: bijective XCD remap of the (x,y) plane (requires gx*gy % 8 == 0).
// ---------------------------------------------------------------------------
template<bool OUT_BF16, bool RES, bool HAS_BIAS>
__global__ __launch_bounds__(256, 2) void gemm2(
    const ushort* __restrict__ A, int lda, long long sA,
    const ushort* __restrict__ Bt, int ldb, long long sB,
    const float* __restrict__ bias, const float* __restrict__ res,
    void* __restrict__ Cv, long long sC,
    int M, int N, int K, float alpha) {
    __shared__ ushort As[3][256 * 32];
    __shared__ ushort Bs[3][128 * 32];
    int t = threadIdx.x;
    int z = blockIdx.z;

    // T1: XCD-aware remap within the (x,y) plane.
    int gx = gridDim.x;
    int lin = blockIdx.y * gx + blockIdx.x;
    int nwg = gx * gridDim.y;
    int swz = (lin & 7) * (nwg >> 3) + (lin >> 3);
    int bx = swz % gx, by = swz / gx;

    const ushort* Ab = A  + (size_t)z * sA;
    const ushort* Bb = Bt + (size_t)z * sB;
    int m0 = by * 256, n0 = bx * 128;
    int lane = t & 63, w = t >> 6, wr = w >> 1, wc = w & 1;

    f32x4 acc[8][4];
    #pragma unroll
    for (int i = 0; i < 8; i++)
        #pragma unroll
        for (int j = 0; j < 4; j++) acc[i][j] = (f32x4){0.f, 0.f, 0.f, 0.f};

    int kq = lane >> 4;              // logical k-quad 0..3 (8 ushorts each)
    int rA = wr * 128 + (lane & 15);
    int rB = wc * 64 + (lane & 15);
    const int NT = K >> 5;

    // stage one K-tile: A 256x32 (4 chunks/thread), B 128x32 (2 chunks/thread)
    // LDS slot (row, g) receives global k-part g ^ ((row>>1)&3)
    auto stage = [&](int kt, int buf) {
        int ko = kt * 32;
        #pragma unroll
        for (int i = 0; i < 4; i++) {
            int c = t + i * 256;
            int row = c >> 2, g = (c & 3) ^ ((row >> 1) & 3);
            gll16(Ab + (size_t)(m0 + row) * lda + g * 8 + ko, &As[buf][c * 8]);
        }
        #pragma unroll
        for (int i = 0; i < 2; i++) {
            int c = t + i * 256;
            int row = c >> 2, g = (c & 3) ^ ((row >> 1) & 3);
            gll16(Bb + (size_t)(n0 + row) * ldb + g * 8 + ko, &Bs[buf][c * 8]);
        }
    };

    auto compute = [&](int buf) {
        s16x8 b[4];
        #pragma unroll
        for (int i = 0; i < 4; i++) {
            int row = rB + i * 16;
            int pg = kq ^ ((row >> 1) & 3);
            b[i] = *(const s16x8*)&Bs[buf][row * 32 + pg * 8];
        }
        #pragma unroll
        for (int half = 0; half < 2; half++) {
            s16x8 a[4];
            #pragma unroll
            for (int i = 0; i < 4; i++) {
                int row = rA + (half * 4 + i) * 16;
                int pg = kq ^ ((row >> 1) & 3);
                a[i] = *(const s16x8*)&As[buf][row * 32 + pg * 8];
            }
            #pragma unroll
            for (int mi = 0; mi < 4; mi++)
                #pragma unroll
                for (int ni = 0; ni < 4; ni++)
                    acc[half * 4 + mi][ni] =
                        __builtin_amdgcn_mfma_f32_16x16x32_bf16(
                            a[mi], b[ni], acc[half * 4 + mi][ni], 0, 0, 0);
        }
    };

    stage(0, 0);
    stage(1, 1);
    for (int kt = 0; kt < NT - 1; ++kt) {
        // boundary: buf[kt] ready (oldest 6 loads retired); newest 6 in flight
        asm volatile("s_waitcnt vmcnt(6)\n\ts_barrier" ::: "memory");
        if (kt + 2 < NT) stage(kt + 2, (kt + 2) % 3);
        compute(kt % 3);
    }
    asm volatile("s_waitcnt vmcnt(0)\n\ts_barrier" ::: "memory");
    compute((NT - 1) % 3);

    float*  Cf = (float*)Cv  + (size_t)z * sC;
    ushort* Cb = (ushort*)Cv + (size_t)z * sC;
    const float* resz = RES ? res + (size_t)z * sC : nullptr;
    #pragma unroll
    for (int ni = 0; ni < 4; ni++) {
        int col = n0 + wc * 64 + ni * 16 + (lane & 15);
        float bv_ = HAS_BIAS ? bias[col] : 0.f;
        #pragma unroll
        for (int mi = 0; mi < 8; mi++) {
            int rowb = m0 + wr * 128 + mi * 16 + (lane >> 4) * 4;
            #pragma unroll
            for (int r = 0; r < 4; r++) {
                size_t off = (size_t)(rowb + r) * N + col;
                float vout = (acc[mi][ni][r] + bv_) * alpha;
                if (RES) vout += resz[off];
                if (OUT_BF16) Cb[off] = f2bf(vout);
                else          Cf[off] = vout;
            }
        }
    }
}

// ---------------------------------------------------------------------------
// Row softmax on bf16 S, in place. One block per row (4096 bf16).
// ---------------------------------------------------------------------------
__global__ __launch_bounds__(256) void softmax_bf16(ushort* __restrict__ S) {
    ushort* rp = S + (size_t)blockIdx.x * 4096;
    int t = threadIdx.x;
    s16x8 v0 = ((const s16x8*)rp)[t];
    s16x8 v1 = ((const s16x8*)rp)[t + 256];
    float f[16];
    #pragma unroll
    for (int j = 0; j < 8; j++) { f[j] = bf2f((ushort)v0[j]); f[8 + j] = bf2f((ushort)v1[j]); }

    float m = -1e30f;
    #pragma unroll
    for (int j = 0; j < 16; j++) m = fmaxf(m, f[j]);
    for (int off = 32; off > 0; off >>= 1) m = fmaxf(m, __shfl_xor(m, off));
    __shared__ float red1[4], red2[4];
    int w = t >> 6, lane = t & 63;
    if (lane == 0) red1[w] = m;
    __syncthreads();
    m = fmaxf(fmaxf(red1[0], red1[1]), fmaxf(red1[2], red1[3]));

    float s = 0.f;
    #pragma unroll
    for (int j = 0; j < 16; j++) { f[j] = __expf(f[j] - m); s += f[j]; }
    for (int off = 32; off > 0; off >>= 1) s += __shfl_xor(s, off);
    if (lane == 0) red2[w] = s;
    __syncthreads();
    s = red2[0] + red2[1] + red2[2] + red2[3];
    float inv = 1.f / s;

    s16x8 o0, o1;
    #pragma unroll
    for (int j = 0; j < 8; j++) {
        o0[j] = (short)f2bf(f[j] * inv);
        o1[j] = (short)f2bf(f[8 + j] * inv);
    }
    ((s16x8*)rp)[t] = o0;
    ((s16x8*)rp)[t + 256] = o1;
}

// ---------------------------------------------------------------------------
extern "C" void kernel_launch(void* const* d_in, const int* in_sizes, int n_in,
                              void* d_out, int out_size, void* d_ws, size_t ws_size,
                              hipStream_t stream) {
    const float* x     = (const float*)d_in[0];
    const float* gamma = (const float*)d_in[1];
    const float* beta  = (const float*)d_in[2];
    const float* wq = (const float*)d_in[3];  const float* bq = (const float*)d_in[4];
    const float* wk = (const float*)d_in[5];  const float* bk = (const float*)d_in[6];
    const float* wv = (const float*)d_in[7];  const float* bv = (const float*)d_in[8];
    const float* wp = (const float*)d_in[9];  const float* bp = (const float*)d_in[10];
    float* out = (float*)d_out;

    char* ws = (char*)d_ws;
    size_t off = 0;
    auto alloc = [&](size_t bytes) {
        void* p = ws + off;
        off += (bytes + 255) & ~(size_t)255;
        return p;
    };
    const long long QO  = 4096LL * 512;          // per-batch attn-out elems
    const long long SS  = 4096LL * 4096;         // per-batch S elems (bf16)
    const long long QSA = 4096LL * 1536;         // per-batch qkv row stride

    float2* stats   = (float2*)alloc(128 * sizeof(float2));
    float2* partial = (float2*)alloc(8192 * sizeof(float2));
    ushort* wcat = (ushort*)alloc((size_t)1536 * 512 * 2);
    ushort* wtp  = (ushort*)alloc((size_t)512 * 512 * 2);
    float*  bcat = (float*)alloc(1536 * sizeof(float));
    ushort* hb   = (ushort*)alloc((size_t)16384 * 512 * 2);   // h_, later attn out
    ushort* qkvb = (ushort*)alloc((size_t)16384 * 1536 * 2);  // fused q|k|v
    ushort* vtb  = (ushort*)alloc((size_t)16384 * 512 * 2);
    bool big = ws_size >= (off + (size_t)4 * SS * 2 + (1 << 20));
    ushort* Sb = (ushort*)alloc(((size_t)(big ? 4 : 2)) * SS * 2);
    ushort* aob = hb;
    (void)in_sizes; (void)n_in; (void)out_size;

    const float scale = 0.044194173824159216f;   // 512^-0.5, folded into wq/bq

    gn_part<<<256, 256, 0, stream>>>(x, partial);
    gn_reduce<<<1, 128, 0, stream>>>(partial, stats);
    gn_apply<<<2048, 256, 0, stream>>>(x, gamma, beta, stats, hb);
    prep_w<<<dim3(16, 16, 4), dim3(32, 8), 0, stream>>>(wq, wk, wv, wp,
                                                        wcat, wtp, scale);
    bias_cat<<<1, 512, 0, stream>>>(bq, bk, bv, bcat, scale);

    // fused QKV: [16384 x 1536] = h_ @ wcat^T + bcat
    gemm2<true, false, true><<<dim3(12, 64, 1), 256, 0, stream>>>(
        hb, 512, 0, wcat, 512, 0, bcat, nullptr, qkvb, 0,
        16384, 1536, 512, 1.f);
    transpose_v<<<dim3(64, 8, 4), 256, 0, stream>>>(qkvb + 1024, 1536, vtb);

    if (big) {
        gemm2<true, false, false><<<dim3(32, 16, 4), 256, 0, stream>>>(
            qkvb, 1536, QSA, qkvb + 512, 1536, QSA,
            nullptr, nullptr, Sb, SS, 4096, 4096, 512, 1.f);
        softmax_bf16<<<16384, 256, 0, stream>>>(Sb);
        gemm2<true, false, false><<<dim3(4, 16, 4), 256, 0, stream>>>(
            Sb, 4096, SS, vtb, 4096, QO,
            nullptr, nullptr, aob, QO, 4096, 512, 4096, 1.f);
    } else {
        for (int p = 0; p < 2; p++) {
            gemm2<true, false, false><<<dim3(32, 16, 2), 256, 0, stream>>>(
                qkvb + (size_t)p * 2 * QSA, 1536, QSA,
                qkvb + 512 + (size_t)p * 2 * QSA, 1536, QSA,
                nullptr, nullptr, Sb, SS, 4096, 4096, 512, 1.f);
            softmax_bf16<<<8192, 256, 0, stream>>>(Sb);
            gemm2<true, false, false><<<dim3(4, 16, 2), 256, 0, stream>>>(
                Sb, 4096, SS, vtb + (size_t)p * 2 * QO, 4096, QO,
                nullptr, nullptr, aob + (size_t)p * 2 * QO, QO,
                4096, 512, 4096, 1.f);
        }
    }
    gemm2<false, true, true><<<dim3(4, 64, 1), 256, 0, stream>>>(
        aob, 512, 0, wtp, 512, 0, bp, x, out, 0, 16384, 512, 512, 1.f);
}

// Round 7
// 435.977 us; speedup vs baseline: 1.0836x; 1.0836x over previous
//
#include <hip/hip_runtime.h>
#include <hip/hip_bf16.h>

// ---------------------------------------------------------------------------
// AttnBlock: GroupNorm -> fused qkv 1x1conv -> softmax(QK^T*scale)@V -> proj+res
// B=4, HW=4096, C=512, G=32. bf16 MFMA, fp32 accum.
// Round 7: S and QKV GEMMs use a 256x256/BK=64/8-wave 2-dbuf schedule (gemm8:
// counted vmcnt(8), 4-phase compute with setprio around MFMA clusters, XOR
// slot swizzle, 128KB dynamic LDS, 1 block/CU by design). PV and proj revert
// to the round-5 proven gemm2 (BM=128, 3-buf, vmcnt(4), T1+T2).
// ---------------------------------------------------------------------------

typedef __attribute__((ext_vector_type(8))) short s16x8;  // 8 bf16
typedef __attribute__((ext_vector_type(4))) float f32x4;  // MFMA accum

__device__ inline ushort f2bf(float f) {
    union { float f; unsigned u; } v; v.f = f;
    unsigned r = (v.u + 0x7FFFu + ((v.u >> 16) & 1u)) >> 16;
    return (ushort)r;
}
__device__ inline float bf2f(ushort u) {
    union { unsigned u; float f; } v; v.u = ((unsigned)u) << 16;
    return v.f;
}

__device__ inline void gll16(const void* g, void* l) {
    __builtin_amdgcn_global_load_lds(
        (const __attribute__((address_space(1))) void*)g,
        (__attribute__((address_space(3))) void*)l, 16, 0, 0);
}

// ---------------------------------------------------------------------------
// GroupNorm stage 1: contiguous partial sums.
// ---------------------------------------------------------------------------
__global__ __launch_bounds__(256) void gn_part(const float* __restrict__ x,
                                               float2* __restrict__ partial) {
    int blk = blockIdx.x;
    int b = blk >> 6, chunk = blk & 63;
    const float* base = x + ((size_t)b * 4096 + chunk * 64) * 512;
    int t = threadIdx.x;
    int q = t & 127, ph = t >> 7;
    float s = 0.f, ss = 0.f;
    for (int p = ph; p < 64; p += 2) {
        float4 v = *(const float4*)(base + (size_t)p * 512 + q * 4);
        s  += v.x + v.y + v.z + v.w;
        ss += v.x * v.x + v.y * v.y + v.z * v.z + v.w * v.w;
    }
    __shared__ float ls[256], lss[256];
    ls[t] = s; lss[t] = ss;
    __syncthreads();
    if (t < 32) {
        float S1 = 0.f, S2 = 0.f;
        #pragma unroll
        for (int j = 0; j < 4; j++) {
            int i = t * 4 + j;
            S1 += ls[i] + ls[i + 128];
            S2 += lss[i] + lss[i + 128];
        }
        partial[(size_t)blk * 32 + t] = make_float2(S1, S2);
    }
}

__global__ void gn_reduce(const float2* __restrict__ partial,
                          float2* __restrict__ stats) {
    int i = threadIdx.x;   // b*32+g
    if (i < 128) {
        int b = i >> 5, g = i & 31;
        float S1 = 0.f, S2 = 0.f;
        for (int c = 0; c < 64; c++) {
            float2 p = partial[((size_t)(b * 64 + c)) * 32 + g];
            S1 += p.x; S2 += p.y;
        }
        float mean = S1 * (1.f / 65536.f);
        float var  = S2 * (1.f / 65536.f) - mean * mean;
        stats[i] = make_float2(mean, rsqrtf(var + 1e-5f));
    }
}

// ---------------------------------------------------------------------------
// GroupNorm apply + cast to bf16 h_
// ---------------------------------------------------------------------------
__global__ __launch_bounds__(256) void gn_apply(const float* __restrict__ x,
                                                const float* __restrict__ gamma,
                                                const float* __restrict__ beta,
                                                const float2* __restrict__ stats,
                                                ushort* __restrict__ h) {
    const int total = 4 * 4096 * 512 / 4;
    for (int i = blockIdx.x * blockDim.x + threadIdx.x; i < total;
         i += gridDim.x * blockDim.x) {
        int e = i * 4;
        int c = e & 511;
        int b = e >> 21;
        int g = c >> 4;
        float2 st = stats[b * 32 + g];
        float4 v  = *(const float4*)(x + (size_t)e);
        float4 ga = *(const float4*)(gamma + c);
        float4 be = *(const float4*)(beta + c);
        ushort4 o;
        o.x = f2bf((v.x - st.x) * st.y * ga.x + be.x);
        o.y = f2bf((v.y - st.x) * st.y * ga.y + be.y);
        o.z = f2bf((v.z - st.x) * st.y * ga.z + be.z);
        o.w = f2bf((v.w - st.x) * st.y * ga.w + be.w);
        ((ushort4*)h)[i] = o;
    }
}

// ---------------------------------------------------------------------------
// Weight prep: fp32 (K,N) -> bf16 (N,K). z<3 -> wcat slab (q scaled), z=3 -> wtp
// ---------------------------------------------------------------------------
__global__ void prep_w(const float* __restrict__ wq, const float* __restrict__ wk,
                       const float* __restrict__ wv, const float* __restrict__ wp,
                       ushort* __restrict__ wcat, ushort* __restrict__ wtp,
                       float qscale) {
    const float* src; ushort* dst; float al = 1.f;
    switch (blockIdx.z) {
        case 0: src = wq; dst = wcat;               al = qscale; break;
        case 1: src = wk; dst = wcat + 512 * 512;   break;
        case 2: src = wv; dst = wcat + 1024 * 512;  break;
        default: src = wp; dst = wtp;               break;
    }
    __shared__ float tile[32][33];
    int k0 = blockIdx.y * 32, n0 = blockIdx.x * 32;
    int tx = threadIdx.x, ty = threadIdx.y;
    #pragma unroll
    for (int i = 0; i < 4; i++)
        tile[ty + i * 8][tx] = src[(size_t)(k0 + ty + i * 8) * 512 + n0 + tx];
    __syncthreads();
    #pragma unroll
    for (int i = 0; i < 4; i++)
        dst[(size_t)(n0 + ty + i * 8) * 512 + k0 + tx] =
            f2bf(tile[tx][ty + i * 8] * al);
}

__global__ void bias_cat(const float* __restrict__ bq, const float* __restrict__ bk,
                         const float* __restrict__ bv, float* __restrict__ bcat,
                         float qscale) {
    int t = threadIdx.x;
    bcat[t]        = bq[t] * qscale;
    bcat[512 + t]  = bk[t];
    bcat[1024 + t] = bv[t];
}

// ---------------------------------------------------------------------------
// V transpose per batch: (4096 x 512, row stride ist) -> (512 x 4096) bf16
// ---------------------------------------------------------------------------
__global__ __launch_bounds__(256) void transpose_v(const ushort* __restrict__ v,
                                                   int ist,
                                                   ushort* __restrict__ vt) {
    __shared__ ushort tile[64][72];
    int b = blockIdx.z;
    int kv0 = blockIdx.x * 64, c0 = blockIdx.y * 64;
    const ushort* in = v + (size_t)b * 4096 * ist;
    ushort* out = vt + (size_t)b * 512 * 4096;
    int t = threadIdx.x;
    int c4 = t & 15, r = t >> 4;
    #pragma unroll
    for (int i = 0; i < 4; i++) {
        int row = r + i * 16;
        *(ushort4*)&tile[row][c4 * 4] =
            *(const ushort4*)(in + (size_t)(kv0 + row) * ist + c0 + c4 * 4);
    }
    __syncthreads();
    int kv4 = t & 15, rc = t >> 4;
    #pragma unroll
    for (int i = 0; i < 4; i++) {
        int c = rc + i * 16;
        ushort4 o;
        o.x = tile[kv4 * 4 + 0][c];
        o.y = tile[kv4 * 4 + 1][c];
        o.z = tile[kv4 * 4 + 2][c];
        o.w = tile[kv4 * 4 + 3][c];
        *(ushort4*)(out + (size_t)(c0 + c) * 4096 + kv0 + kv4 * 4) = o;
    }
}

// ---------------------------------------------------------------------------
// gemm8: 256x256 tile, BK=64, 512 thr = 8 waves (2Mx4N), per-wave 128x64 out.
// 2-buffer double-buffered 128KB dynamic LDS; per K-tile:
//   issue stage(t+1) [8 gload_lds/thread] -> s_waitcnt vmcnt(8) -> s_barrier
//   -> 4-phase compute (64 MFMA/wave, setprio(1) per 16-MFMA cluster)
//   -> s_barrier  (frees buf for next stage; race-free, see round-5 proof)
// LDS swizzle: row of 8x16B slots, slot' = slot ^ (row&7); applied on the
// staging SOURCE address (dest linear, per gload_lds rules) and on ds_read.
// T1 bijective XCD remap of (x,y) plane (needs gx*gy % 8 == 0).
// ---------------------------------------------------------------------------
template<bool OUT_BF16, bool HAS_BIAS>
__global__ __launch_bounds__(512, 2) void gemm8(
    const ushort* __restrict__ A, int lda, long long sA,
    const ushort* __restrict__ Bt, int ldb, long long sB,
    const float* __restrict__ bias,
    void* __restrict__ Cv, long long sC,
    int M, int N, int K, float alpha) {
    extern __shared__ __align__(16) ushort lds_[];   // 2 x (A 256x64 + B 256x64)
    int t = threadIdx.x;
    int z = blockIdx.z;

    // T1 XCD remap
    int gx = gridDim.x;
    int lin = blockIdx.y * gx + blockIdx.x;
    int nwg = gx * gridDim.y;
    int swz = (lin & 7) * (nwg >> 3) + (lin >> 3);
    int bx = swz % gx, by = swz / gx;

    const ushort* Ab = A  + (size_t)z * sA;
    const ushort* Bb = Bt + (size_t)z * sB;
    int m0 = by * 256, n0 = bx * 256;
    int lane = t & 63, w = t >> 6, wr = w >> 2, wc = w & 3;

    f32x4 acc[8][4];
    #pragma unroll
    for (int i = 0; i < 8; i++)
        #pragma unroll
        for (int j = 0; j < 4; j++) acc[i][j] = (f32x4){0.f, 0.f, 0.f, 0.f};

    int kq = lane >> 4;                       // 0..3
    int rA0 = wr * 128 + (lane & 15);         // A row base for this lane
    int rB0 = wc * 64 + (lane & 15);          // B row (=out col) base
    const int NT = K >> 6;                    // BK = 64

    // stage one K-tile (A 2048 chunks + B 2048 chunks of 16B, 8 per thread)
    auto stage = [&](int kt, int bb) {
        int k0 = kt * 64;
        ushort* Ad = lds_ + bb * 32768;
        ushort* Bd = Ad + 16384;
        #pragma unroll
        for (int i = 0; i < 4; i++) {
            int c = t + i * 512;
            int row = c >> 3, ks = (c & 7) ^ (row & 7);
            gll16(Ab + (size_t)(m0 + row) * lda + ks * 8 + k0, Ad + c * 8);
        }
        #pragma unroll
        for (int i = 0; i < 4; i++) {
            int c = t + i * 512;
            int row = c >> 3, ks = (c & 7) ^ (row & 7);
            gll16(Bb + (size_t)(n0 + row) * ldb + ks * 8 + k0, Bd + c * 8);
        }
    };

    auto rdA = [&](const ushort* At, int row, int ksh) -> s16x8 {
        int sl = (ksh * 4 + kq) ^ (row & 7);
        return *(const s16x8*)&At[row * 64 + sl * 8];
    };

    auto compute = [&](int bb) {
        const ushort* At = lds_ + bb * 32768;
        const ushort* Bl = At + 16384;
        s16x8 a8[8], b01[4], b23[4];
        // phase 0: a[mi0..3][ks01] + b[ni0..1][ks01] -> mi0-3 x ni0-1
        #pragma unroll
        for (int mi = 0; mi < 4; mi++)
            #pragma unroll
            for (int ks = 0; ks < 2; ks++)
                a8[mi * 2 + ks] = rdA(At, rA0 + mi * 16, ks);
        #pragma unroll
        for (int ni = 0; ni < 2; ni++)
            #pragma unroll
            for (int ks = 0; ks < 2; ks++)
                b01[ni * 2 + ks] = rdA(Bl, rB0 + ni * 16, ks);
        __builtin_amdgcn_s_setprio(1);
        #pragma unroll
        for (int mi = 0; mi < 4; mi++)
            #pragma unroll
            for (int ni = 0; ni < 2; ni++)
                #pragma unroll
                for (int ks = 0; ks < 2; ks++)
                    acc[mi][ni] = __builtin_amdgcn_mfma_f32_16x16x32_bf16(
                        a8[mi * 2 + ks], b01[ni * 2 + ks], acc[mi][ni], 0, 0, 0);
        __builtin_amdgcn_s_setprio(0);
        // phase 1: + b[ni2..3][ks01] -> mi0-3 x ni2-3
        #pragma unroll
        for (int ni = 0; ni < 2; ni++)
            #pragma unroll
            for (int ks = 0; ks < 2; ks++)
                b23[ni * 2 + ks] = rdA(Bl, rB0 + (ni + 2) * 16, ks);
        __builtin_amdgcn_s_setprio(1);
        #pragma unroll
        for (int mi = 0; mi < 4; mi++)
            #pragma unroll
            for (int ni = 0; ni < 2; ni++)
                #pragma unroll
                for (int ks = 0; ks < 2; ks++)
                    acc[mi][ni + 2] = __builtin_amdgcn_mfma_f32_16x16x32_bf16(
                        a8[mi * 2 + ks], b23[ni * 2 + ks], acc[mi][ni + 2], 0, 0, 0);
        __builtin_amdgcn_s_setprio(0);
        // phase 2: new a[mi4..7][ks01] -> mi4-7 x ni2-3
        #pragma unroll
        for (int mi = 0; mi < 4; mi++)
            #pragma unroll
            for (int ks = 0; ks < 2; ks++)
                a8[mi * 2 + ks] = rdA(At, rA0 + (mi + 4) * 16, ks);
        __builtin_amdgcn_s_setprio(1);
        #pragma unroll
        for (int mi = 0; mi < 4; mi++)
            #pragma unroll
            for (int ni = 0; ni < 2; ni++)
                #pragma unroll
                for (int ks = 0; ks < 2; ks++)
                    acc[mi + 4][ni + 2] = __builtin_amdgcn_mfma_f32_16x16x32_bf16(
                        a8[mi * 2 + ks], b23[ni * 2 + ks], acc[mi + 4][ni + 2], 0, 0, 0);
        __builtin_amdgcn_s_setprio(0);
        // phase 3: mi4-7 x ni0-1 (reuse a8, b01)
        __builtin_amdgcn_s_setprio(1);
        #pragma unroll
        for (int mi = 0; mi < 4; mi++)
            #pragma unroll
            for (int ni = 0; ni < 2; ni++)
                #pragma unroll
                for (int ks = 0; ks < 2; ks++)
                    acc[mi + 4][ni] = __builtin_amdgcn_mfma_f32_16x16x32_bf16(
                        a8[mi * 2 + ks], b01[ni * 2 + ks], acc[mi + 4][ni], 0, 0, 0);
        __builtin_amdgcn_s_setprio(0);
    };

    stage(0, 0);
    for (int kt = 0; kt < NT; ++kt) {
        if (kt + 1 < NT) {
            stage(kt + 1, (kt + 1) & 1);
            asm volatile("s_waitcnt vmcnt(8)\n\ts_barrier" ::: "memory");
        } else {
            asm volatile("s_waitcnt vmcnt(0)\n\ts_barrier" ::: "memory");
        }
        compute(kt & 1);
        asm volatile("s_barrier" ::: "memory");
    }

    float*  Cf = (float*)Cv  + (size_t)z * sC;
    ushort* Cb = (ushort*)Cv + (size_t)z * sC;
    #pragma unroll
    for (int ni = 0; ni < 4; ni++) {
        int col = n0 + wc * 64 + ni * 16 + (lane & 15);
        float bv_ = HAS_BIAS ? bias[col] : 0.f;
        #pragma unroll
        for (int mi = 0; mi < 8; mi++) {
            int rowb = m0 + wr * 128 + mi * 16 + (lane >> 4) * 4;
            #pragma unroll
            for (int r = 0; r < 4; r++) {
                size_t off = (size_t)(rowb + r) * N + col;
                float vout = (acc[mi][ni][r] + bv_) * alpha;
                if (OUT_BF16) Cb[off] = f2bf(vout);
                else          Cf[off] = vout;
            }
        }
    }
}

// ---------------------------------------------------------------------------
// Round-5 gemm2 (proven): 128x128 tile, BK=32, 3-buffer depth-2, vmcnt(4),
// T1 XCD remap + T2 source-side swizzle. Used for PV and proj.
// ---------------------------------------------------------------------------
template<bool OUT_BF16, bool RES, bool HAS_BIAS>
__global__ __launch_bounds__(256, 3) void gemm2(
    const ushort* __restrict__ A, int lda, long long sA,
    const ushort* __restrict__ Bt, int ldb, long long sB,
    const float* __restrict__ bias, const float* __restrict__ res,
    void* __restrict__ Cv, long long sC,
    int M, int N, int K, float alpha) {
    __shared__ ushort As[3][128 * 32];
    __shared__ ushort Bs[3][128 * 32];
    int t = threadIdx.x;
    int z = blockIdx.z;

    int gx = gridDim.x;
    int lin = blockIdx.y * gx + blockIdx.x;
    int nwg = gx * gridDim.y;
    int swz = (lin & 7) * (nwg >> 3) + (lin >> 3);
    int bx = swz % gx, by = swz / gx;

    const ushort* Ab = A  + (size_t)z * sA;
    const ushort* Bb = Bt + (size_t)z * sB;
    int m0 = by * 128, n0 = bx * 128;
    int lane = t & 63, w = t >> 6, wr = w >> 1, wc = w & 1;

    f32x4 acc[4][4];
    #pragma unroll
    for (int i = 0; i < 4; i++)
        #pragma unroll
        for (int j = 0; j < 4; j++) acc[i][j] = (f32x4){0.f, 0.f, 0.f, 0.f};

    int kq = lane >> 4;
    int rA = wr * 64 + (lane & 15);
    int rB = wc * 64 + (lane & 15);
    const int NT = K >> 5;

    auto stage = [&](int kt, int buf) {
        int ko = kt * 32;
        #pragma unroll
        for (int i = 0; i < 2; i++) {
            int c = t + i * 256;
            int row = c >> 2, g = (c & 3) ^ ((row >> 1) & 3);
            gll16(Ab + (size_t)(m0 + row) * lda + g * 8 + ko, &As[buf][c * 8]);
        }
        #pragma unroll
        for (int i = 0; i < 2; i++) {
            int c = t + i * 256;
            int row = c >> 2, g = (c & 3) ^ ((row >> 1) & 3);
            gll16(Bb + (size_t)(n0 + row) * ldb + g * 8 + ko, &Bs[buf][c * 8]);
        }
    };

    auto compute = [&](int buf) {
        s16x8 a[4], b[4];
        #pragma unroll
        for (int i = 0; i < 4; i++) {
            int row = rA + i * 16;
            int pg = kq ^ ((row >> 1) & 3);
            a[i] = *(const s16x8*)&As[buf][row * 32 + pg * 8];
        }
        #pragma unroll
        for (int i = 0; i < 4; i++) {
            int row = rB + i * 16;
            int pg = kq ^ ((row >> 1) & 3);
            b[i] = *(const s16x8*)&Bs[buf][row * 32 + pg * 8];
        }
        #pragma unroll
        for (int mi = 0; mi < 4; mi++)
            #pragma unroll
            for (int ni = 0; ni < 4; ni++)
                acc[mi][ni] = __builtin_amdgcn_mfma_f32_16x16x32_bf16(
                    a[mi], b[ni], acc[mi][ni], 0, 0, 0);
    };

    stage(0, 0);
    stage(1, 1);
    for (int kt = 0; kt < NT - 1; ++kt) {
        asm volatile("s_waitcnt vmcnt(4)\n\ts_barrier" ::: "memory");
        if (kt + 2 < NT) stage(kt + 2, (kt + 2) % 3);
        compute(kt % 3);
    }
    asm volatile("s_waitcnt vmcnt(0)\n\ts_barrier" ::: "memory");
    compute((NT - 1) % 3);

    float*  Cf = (float*)Cv  + (size_t)z * sC;
    ushort* Cb = (ushort*)Cv + (size_t)z * sC;
    const float* resz = RES ? res + (size_t)z * sC : nullptr;
    #pragma unroll
    for (int ni = 0; ni < 4; ni++) {
        int col = n0 + wc * 64 + ni * 16 + (lane & 15);
        float bv_ = HAS_BIAS ? bias[col] : 0.f;
        #pragma unroll
        for (int mi = 0; mi < 4; mi++) {
            int rowb = m0 + wr * 64 + mi * 16 + (lane >> 4) * 4;
            #pragma unroll
            for (int r = 0; r < 4; r++) {
                size_t off = (size_t)(rowb + r) * N + col;
                float vout = (acc[mi][ni][r] + bv_) * alpha;
                if (RES) vout += resz[off];
                if (OUT_BF16) Cb[off] = f2bf(vout);
                else          Cf[off] = vout;
            }
        }
    }
}

// ---------------------------------------------------------------------------
// Row softmax on bf16 S, in place. One block per row (4096 bf16).
// ---------------------------------------------------------------------------
__global__ __launch_bounds__(256) void softmax_bf16(ushort* __restrict__ S) {
    ushort* rp = S + (size_t)blockIdx.x * 4096;
    int t = threadIdx.x;
    s16x8 v0 = ((const s16x8*)rp)[t];
    s16x8 v1 = ((const s16x8*)rp)[t + 256];
    float f[16];
    #pragma unroll
    for (int j = 0; j < 8; j++) { f[j] = bf2f((ushort)v0[j]); f[8 + j] = bf2f((ushort)v1[j]); }

    float m = -1e30f;
    #pragma unroll
    for (int j = 0; j < 16; j++) m = fmaxf(m, f[j]);
    for (int off = 32; off > 0; off >>= 1) m = fmaxf(m, __shfl_xor(m, off));
    __shared__ float red1[4], red2[4];
    int w = t >> 6, lane = t & 63;
    if (lane == 0) red1[w] = m;
    __syncthreads();
    m = fmaxf(fmaxf(red1[0], red1[1]), fmaxf(red1[2], red1[3]));

    float s = 0.f;
    #pragma unroll
    for (int j = 0; j < 16; j++) { f[j] = __expf(f[j] - m); s += f[j]; }
    for (int off = 32; off > 0; off >>= 1) s += __shfl_xor(s, off);
    if (lane == 0) red2[w] = s;
    __syncthreads();
    s = red2[0] + red2[1] + red2[2] + red2[3];
    float inv = 1.f / s;

    s16x8 o0, o1;
    #pragma unroll
    for (int j = 0; j < 8; j++) {
        o0[j] = (short)f2bf(f[j] * inv);
        o1[j] = (short)f2bf(f[8 + j] * inv);
    }
    ((s16x8*)rp)[t] = o0;
    ((s16x8*)rp)[t + 256] = o1;
}

// ---------------------------------------------------------------------------
extern "C" void kernel_launch(void* const* d_in, const int* in_sizes, int n_in,
                              void* d_out, int out_size, void* d_ws, size_t ws_size,
                              hipStream_t stream) {
    const float* x     = (const float*)d_in[0];
    const float* gamma = (const float*)d_in[1];
    const float* beta  = (const float*)d_in[2];
    const float* wq = (const float*)d_in[3];  const float* bq = (const float*)d_in[4];
    const float* wk = (const float*)d_in[5];  const float* bk = (const float*)d_in[6];
    const float* wv = (const float*)d_in[7];  const float* bv = (const float*)d_in[8];
    const float* wp = (const float*)d_in[9];  const float* bp = (const float*)d_in[10];
    float* out = (float*)d_out;

    char* ws = (char*)d_ws;
    size_t off = 0;
    auto alloc = [&](size_t bytes) {
        void* p = ws + off;
        off += (bytes + 255) & ~(size_t)255;
        return p;
    };
    const long long QO  = 4096LL * 512;          // per-batch attn-out elems
    const long long SS  = 4096LL * 4096;         // per-batch S elems (bf16)
    const long long QSA = 4096LL * 1536;         // per-batch qkv row stride

    float2* stats   = (float2*)alloc(128 * sizeof(float2));
    float2* partial = (float2*)alloc(8192 * sizeof(float2));
    ushort* wcat = (ushort*)alloc((size_t)1536 * 512 * 2);
    ushort* wtp  = (ushort*)alloc((size_t)512 * 512 * 2);
    float*  bcat = (float*)alloc(1536 * sizeof(float));
    ushort* hb   = (ushort*)alloc((size_t)16384 * 512 * 2);   // h_, later attn out
    ushort* qkvb = (ushort*)alloc((size_t)16384 * 1536 * 2);  // fused q|k|v
    ushort* vtb  = (ushort*)alloc((size_t)16384 * 512 * 2);
    bool big = ws_size >= (off + (size_t)4 * SS * 2 + (1 << 20));
    ushort* Sb = (ushort*)alloc(((size_t)(big ? 4 : 2)) * SS * 2);
    ushort* aob = hb;
    (void)in_sizes; (void)n_in; (void)out_size;

    const float scale = 0.044194173824159216f;   // 512^-0.5, folded into wq/bq

    // allow 128KB dynamic LDS for gemm8 (host-side, graph-capture safe)
    hipFuncSetAttribute(reinterpret_cast<const void*>(&gemm8<true, true>),
                        hipFuncAttributeMaxDynamicSharedMemorySize, 131072);
    hipFuncSetAttribute(reinterpret_cast<const void*>(&gemm8<true, false>),
                        hipFuncAttributeMaxDynamicSharedMemorySize, 131072);

    gn_part<<<256, 256, 0, stream>>>(x, partial);
    gn_reduce<<<1, 128, 0, stream>>>(partial, stats);
    gn_apply<<<2048, 256, 0, stream>>>(x, gamma, beta, stats, hb);
    prep_w<<<dim3(16, 16, 4), dim3(32, 8), 0, stream>>>(wq, wk, wv, wp,
                                                        wcat, wtp, scale);
    bias_cat<<<1, 512, 0, stream>>>(bq, bk, bv, bcat, scale);

    // fused QKV: [16384 x 1536] = h_ @ wcat^T + bcat   (256x256 tiles: 6x64)
    gemm8<true, true><<<dim3(6, 64, 1), 512, 131072, stream>>>(
        hb, 512, 0, wcat, 512, 0, bcat, qkvb, 0, 16384, 1536, 512, 1.f);
    transpose_v<<<dim3(64, 8, 4), 256, 0, stream>>>(qkvb + 1024, 1536, vtb);

    if (big) {
        // S = q @ k^T, all 4 batches, 256x256 tiles: 16x16x4
        gemm8<true, false><<<dim3(16, 16, 4), 512, 131072, stream>>>(
            qkvb, 1536, QSA, qkvb + 512, 1536, QSA,
            nullptr, Sb, SS, 4096, 4096, 512, 1.f);
        softmax_bf16<<<16384, 256, 0, stream>>>(Sb);
        gemm2<true, false, false><<<dim3(4, 32, 4), 256, 0, stream>>>(
            Sb, 4096, SS, vtb, 4096, QO,
            nullptr, nullptr, aob, QO, 4096, 512, 4096, 1.f);
    } else {
        for (int p = 0; p < 2; p++) {
            gemm8<true, false><<<dim3(16, 16, 2), 512, 131072, stream>>>(
                qkvb + (size_t)p * 2 * QSA, 1536, QSA,
                qkvb + 512 + (size_t)p * 2 * QSA, 1536, QSA,
                nullptr, Sb, SS, 4096, 4096, 512, 1.f);
            softmax_bf16<<<8192, 256, 0, stream>>>(Sb);
            gemm2<true, false, false><<<dim3(4, 32, 2), 256, 0, stream>>>(
                Sb, 4096, SS, vtb + (size_t)p * 2 * QO, 4096, QO,
                nullptr, nullptr, aob + (size_t)p * 2 * QO, QO,
                4096, 512, 4096, 1.f);
        }
    }
    gemm2<false, true, true><<<dim3(4, 128, 1), 256, 0, stream>>>(
        aob, 512, 0, wtp, 512, 0, bp, x, out, 0, 16384, 512, 512, 1.f);
}